// Round 9
// baseline (21.065 us; speedup 1.0000x reference)
//
#include <hip/hip_runtime.h>

// MorphTEmbedding R9: R6 main kernel + one-time W transpose into d_ws.
// Wt[m][r][d] = W[r][m][d]  (morph-major: each morph's 8x8 block = 256 B
// contiguous) -> per-token random-line footprint drops 26 -> ~14 lines and
// every W access is spatially local. Main kernel otherwise identical to R6.

#define RANK      8
#define NUM_MORPH 10000
#define EMB       512
#define LN_EPS    1e-5f
#define WPB       4                 // waves per block (256 threads)
#define RSTRIDE   80000             // floats between ranks in original W
#define W_ELEMS   (RANK * NUM_MORPH * 8)   // 640000

template <int CTRL>
__device__ __forceinline__ float dpp_add(float v) {
    return v + __int_as_float(__builtin_amdgcn_update_dpp(
        __float_as_int(v), __float_as_int(v), CTRL, 0xf, 0xf, false));
}
__device__ __forceinline__ float rdlane(float v, int l) {
    return __int_as_float(__builtin_amdgcn_readlane(__float_as_int(v), l));
}

// ---- kernel 1: W[r][m][d] -> Wt[m][r*8+d], coalesced writes ----
__global__ __launch_bounds__(256) void transpose_w(
    const float* __restrict__ W, float* __restrict__ Wt) {
    const int t = blockIdx.x * 256 + threadIdx.x;
    if (t >= W_ELEMS) return;
    const int m  = t >> 6;          // morph
    const int rd = t & 63;
    const int r  = rd >> 3;
    const int d  = rd & 7;
    Wt[t] = W[r * RSTRIDE + m * 8 + d];
}

// ---- kernel 2: one wave per token (R6 structure) ----
// TRANSPOSED: gather from Wt (morph-major); else from W (rank-major, R6).
template <bool TRANSPOSED>
__global__ __launch_bounds__(256) void morph_emb_kernel(
    const int* __restrict__ x,       // [n_tok]
    const int* __restrict__ co,      // [NUM_SURF, 3]
    const float* __restrict__ Wp,    // Wt (transposed) or W (original)
    const float* __restrict__ lns,   // [512]
    const float* __restrict__ lnb,   // [512]
    float* __restrict__ out,         // [n_tok, 512]
    int n_tok) {
    const int lane = threadIdx.x & 63;
    const int wid  = blockIdx.x * WPB + (threadIdx.x >> 6);
    const int tok  = (wid < n_tok) ? wid : (n_tok - 1);   // clamp, no divergence

    // LN params (token-invariant): g[j]=lns[j*64+lane]
    float gv[8], bv[8];
#pragma unroll
    for (int j = 0; j < 8; ++j) {
        gv[j] = lns[j * 64 + lane];
        bv[j] = lnb[j * 64 + lane];
    }

    // token chain (wave-uniform values)
    const int s  = x[tok];
    const int m0 = co[s * 3 + 0];
    const int m1 = co[s * 3 + 1];
    const int m2 = co[s * 3 + 2];

    // A distribution: lane (r=lane>>3, d=lane&7) holds W[r, m0, d] — ONE load
    float a_mine;
    const float* pb;
    const float* pc;
    int pstride;
    if (TRANSPOSED) {
        a_mine  = Wp[m0 * 64 + lane];                 // coalesced 256B
        pb      = Wp + m1 * 64 + (lane >> 3);         // 256B region
        pc      = Wp + m2 * 64 + (lane & 7);          // 256B region
        pstride = 8;
    } else {
        a_mine  = Wp[(size_t)(lane >> 3) * RSTRIDE + (size_t)m0 * 8 + (lane & 7)];
        pb      = Wp + (size_t)m1 * 8 + (lane >> 3);
        pc      = Wp + (size_t)m2 * 8 + (lane & 7);
        pstride = RSTRIDE;
    }

    float p[RANK];
#pragma unroll
    for (int r = 0; r < RANK; ++r)
        p[r] = pb[r * pstride] * pc[r * pstride];

    // acc[j] = sum_r p[r] * A[r][j]; A via readlane -> SGPR operand of v_fmac
    float acc[8] = {0.f, 0.f, 0.f, 0.f, 0.f, 0.f, 0.f, 0.f};
#pragma unroll
    for (int r = 0; r < RANK; ++r) {
#pragma unroll
        for (int j = 0; j < 8; ++j)
            acc[j] = fmaf(p[r], rdlane(a_mine, r * 8 + j), acc[j]);
    }

    // ---- LayerNorm stats: DPP row-16 reduce + 4 readlanes (zero DS) ----
    float sm = 0.f, sq = 0.f;
#pragma unroll
    for (int j = 0; j < 8; ++j) { sm += acc[j]; sq += acc[j] * acc[j]; }
    sm = dpp_add<0xB1>(sm);  sq = dpp_add<0xB1>(sq);
    sm = dpp_add<0x4E>(sm);  sq = dpp_add<0x4E>(sq);
    sm = dpp_add<0x141>(sm); sq = dpp_add<0x141>(sq);
    sm = dpp_add<0x140>(sm); sq = dpp_add<0x140>(sq);
    const float tot_s = (rdlane(sm, 0) + rdlane(sm, 16)) +
                        (rdlane(sm, 32) + rdlane(sm, 48));
    const float tot_q = (rdlane(sq, 0) + rdlane(sq, 16)) +
                        (rdlane(sq, 32) + rdlane(sq, 48));
    const float mu = tot_s * (1.0f / EMB);
    const float rs = rsqrtf(tot_q * (1.0f / EMB) - mu * mu + LN_EPS);

    // ---- normalize + store: 8 fully-coalesced 256B dword stores ----
    if (wid < n_tok) {
        float* op = out + (size_t)wid * EMB + lane;
#pragma unroll
        for (int j = 0; j < 8; ++j)
            op[j * 64] = (acc[j] - mu) * rs * gv[j] + bv[j];
    }
}

extern "C" void kernel_launch(void* const* d_in, const int* in_sizes, int n_in,
                              void* d_out, int out_size, void* d_ws, size_t ws_size,
                              hipStream_t stream) {
    const int*   x   = (const int*)d_in[0];
    const int*   co  = (const int*)d_in[1];
    const float* W   = (const float*)d_in[2];
    const float* lns = (const float*)d_in[3];
    const float* lnb = (const float*)d_in[4];
    float*       out = (float*)d_out;

    const int n_tok  = in_sizes[0];                 // 16384
    const int blocks = (n_tok + WPB - 1) / WPB;     // 4096

    if (ws_size >= (size_t)W_ELEMS * sizeof(float)) {
        float* Wt = (float*)d_ws;
        transpose_w<<<(W_ELEMS + 255) / 256, 256, 0, stream>>>(W, Wt);
        morph_emb_kernel<true><<<blocks, WPB * 64, 0, stream>>>(
            x, co, Wt, lns, lnb, out, n_tok);
    } else {
        morph_emb_kernel<false><<<blocks, WPB * 64, 0, stream>>>(
            x, co, W, lns, lnb, out, n_tok);
    }
}

// Round 10
// 14.166 us; speedup vs baseline: 1.4870x; 1.4870x over previous
//
#include <hip/hip_runtime.h>

// MorphTEmbedding R10: R6 verbatim (zero-DS, one wave/token, 16.5us) with ONE
// change: output stores are nontemporal (no L2 allocate). Theory: the 33.5MB
// output stream (~4.2MB/XCD) evicts W (2.56MB) from each XCD L2 every replay,
// forcing random HBM re-fetch of W each iteration. nt stores keep W resident.

#define RANK      8
#define NUM_MORPH 10000
#define EMB       512
#define LN_EPS    1e-5f
#define WPB       4                 // waves per block (256 threads)
#define RSTRIDE   80000             // floats between ranks in W

template <int CTRL>
__device__ __forceinline__ float dpp_add(float v) {
    return v + __int_as_float(__builtin_amdgcn_update_dpp(
        __float_as_int(v), __float_as_int(v), CTRL, 0xf, 0xf, false));
}
__device__ __forceinline__ float rdlane(float v, int l) {
    return __int_as_float(__builtin_amdgcn_readlane(__float_as_int(v), l));
}

__global__ __launch_bounds__(256) void morph_emb_kernel(
    const int* __restrict__ x,       // [n_tok]
    const int* __restrict__ co,      // [NUM_SURF, 3]
    const float* __restrict__ W,     // [RANK, NUM_MORPH, 8]
    const float* __restrict__ lns,   // [512]
    const float* __restrict__ lnb,   // [512]
    float* __restrict__ out,         // [n_tok, 512]
    int n_tok) {
    const int lane = threadIdx.x & 63;
    const int wid  = blockIdx.x * WPB + (threadIdx.x >> 6);
    const int tok  = (wid < n_tok) ? wid : (n_tok - 1);   // clamp, no divergence

    // LN params (token-invariant): g[j]=lns[j*64+lane]
    float gv[8], bv[8];
#pragma unroll
    for (int j = 0; j < 8; ++j) {
        gv[j] = lns[j * 64 + lane];
        bv[j] = lnb[j * 64 + lane];
    }

    // token chain (wave-uniform values, plain loads)
    const int s  = x[tok];
    const int m0 = co[s * 3 + 0];
    const int m1 = co[s * 3 + 1];
    const int m2 = co[s * 3 + 2];

    // A distribution: lane (r=lane>>3, d=lane&7) holds W[r, m0, d] — ONE load
    const float a_mine =
        W[(size_t)(lane >> 3) * RSTRIDE + (size_t)m0 * 8 + (lane & 7)];

    // B,C per-lane scalars (broadcast loads, 32B footprint each)
    const float* pb = W + (size_t)m1 * 8 + (lane >> 3);
    const float* pc = W + (size_t)m2 * 8 + (lane & 7);
    float p[RANK];
#pragma unroll
    for (int r = 0; r < RANK; ++r)
        p[r] = pb[r * RSTRIDE] * pc[r * RSTRIDE];

    // acc[j] = sum_r p[r] * A[r][j]; A via readlane -> SGPR operand of v_fmac
    float acc[8] = {0.f, 0.f, 0.f, 0.f, 0.f, 0.f, 0.f, 0.f};
#pragma unroll
    for (int r = 0; r < RANK; ++r) {
#pragma unroll
        for (int j = 0; j < 8; ++j)
            acc[j] = fmaf(p[r], rdlane(a_mine, r * 8 + j), acc[j]);
    }

    // ---- LayerNorm stats: DPP row-16 reduce + 4 readlanes (zero DS) ----
    float sm = 0.f, sq = 0.f;
#pragma unroll
    for (int j = 0; j < 8; ++j) { sm += acc[j]; sq += acc[j] * acc[j]; }
    sm = dpp_add<0xB1>(sm);  sq = dpp_add<0xB1>(sq);
    sm = dpp_add<0x4E>(sm);  sq = dpp_add<0x4E>(sq);
    sm = dpp_add<0x141>(sm); sq = dpp_add<0x141>(sq);
    sm = dpp_add<0x140>(sm);  sq = dpp_add<0x140>(sq);
    const float tot_s = (rdlane(sm, 0) + rdlane(sm, 16)) +
                        (rdlane(sm, 32) + rdlane(sm, 48));
    const float tot_q = (rdlane(sq, 0) + rdlane(sq, 16)) +
                        (rdlane(sq, 32) + rdlane(sq, 48));
    const float mu = tot_s * (1.0f / EMB);
    const float rs = rsqrtf(tot_q * (1.0f / EMB) - mu * mu + LN_EPS);

    // ---- normalize + store: 8 coalesced 256B dword stores, NONTEMPORAL ----
    if (wid < n_tok) {
        float* op = out + (size_t)wid * EMB + lane;
#pragma unroll
        for (int j = 0; j < 8; ++j)
            __builtin_nontemporal_store((acc[j] - mu) * rs * gv[j] + bv[j],
                                        op + j * 64);
    }
}

extern "C" void kernel_launch(void* const* d_in, const int* in_sizes, int n_in,
                              void* d_out, int out_size, void* d_ws, size_t ws_size,
                              hipStream_t stream) {
    const int*   x   = (const int*)d_in[0];
    const int*   co  = (const int*)d_in[1];
    const float* W   = (const float*)d_in[2];
    const float* lns = (const float*)d_in[3];
    const float* lnb = (const float*)d_in[4];
    float*       out = (float*)d_out;

    const int n_tok  = in_sizes[0];                 // 16384
    const int blocks = (n_tok + WPB - 1) / WPB;     // 4096
    morph_emb_kernel<<<blocks, WPB * 64, 0, stream>>>(x, co, W, lns, lnb, out, n_tok);
}